// Round 3
// baseline (382.777 us; speedup 1.0000x reference)
//
#include <hip/hip_runtime.h>
#include <hip/hip_bf16.h>

// Problem constants
#define NB     32
#define CIN    256
#define LIN    4096
#define COUT   256
#define KW     9
#define NGRP   4
#define CDIM   128
#define CPG    64          // channels per group (both in and out)
#define LT     128         // l-tile per iteration
#define NROWS  136         // LT + 2*PAD halo rows
#define RP     68          // LDS row stride in bf16 elements (136 B)
#define TPB    4           // tiles per block (software pipeline depth)
#define NTILES 32          // LIN / LT
#define WF_ELEMS (4*4*9*2*64*8)   // g * co16 * k * chunk * lane * j = 294912

typedef __attribute__((ext_vector_type(8))) short short8;    // 8 bf16 = 4 VGPRs (MFMA operand)
typedef __attribute__((ext_vector_type(4))) short short4v;
typedef __attribute__((ext_vector_type(4))) float float4v;
typedef __attribute__((ext_vector_type(4))) unsigned short ushort4v;

// ---- Pack weights (fp32, [co][ci][k]) into MFMA A-fragment-linear bf16 order ----
// wF[((((g*4+co16)*9+k)*2+chunk)*64+lane)*8 + j] = w[co= g*64+co16*16+(lane&15)][ci= chunk*32+(lane>>4)*8+j][k]
__global__ void pack_weights(const float* __restrict__ w, __hip_bfloat16* __restrict__ wF) {
    int tid = blockIdx.x * blockDim.x + threadIdx.x;
    if (tid >= WF_ELEMS) return;
    int j    = tid & 7;
    int lane = (tid >> 3) & 63;
    int rest = tid >> 9;
    int chunk = rest & 1;  rest >>= 1;
    int k     = rest % 9;  rest /= 9;
    int co16  = rest & 3;
    int g     = rest >> 2;
    int co = g * CPG + co16 * 16 + (lane & 15);
    int ci = chunk * 32 + (lane >> 4) * 8 + j;
    wF[tid] = __float2bfloat16(w[(co * CPG + ci) * KW + k]);
}

// ---- ctx[n][co] = c[n] . c_weight[co] + bias[co] : one wave per output, coalesced ----
__global__ __launch_bounds__(256) void ctx_kernel(const float* __restrict__ c,
                                                  const float* __restrict__ cw,
                                                  const float* __restrict__ bias,
                                                  float* __restrict__ ctxb) {
    int gw   = (blockIdx.x * 256 + threadIdx.x) >> 6;   // wave id: [0, 32*256)
    int lane = threadIdx.x & 63;
    int n  = gw >> 8;
    int co = gw & 255;
    float s = c[n * CDIM + lane]      * cw[co * CDIM + lane]
            + c[n * CDIM + 64 + lane] * cw[co * CDIM + 64 + lane];
    #pragma unroll
    for (int off = 32; off; off >>= 1) s += __shfl_down(s, off);
    if (lane == 0) ctxb[gw] = s + bias[co];
}

// ---- Main: software-pipelined implicit-GEMM grouped conv via bf16 MFMA ----
// Per block: TPB consecutive l-tiles, double-buffered LDS. Next tile's global
// loads are issued into registers before the current tile's MFMA phase, so the
// memory pipe stays busy during compute.
__global__ __launch_bounds__(256, 4) void conv_mfma(
    const float* __restrict__ x, const __hip_bfloat16* __restrict__ wF,
    const float* __restrict__ ctxb, float* __restrict__ out)
{
    __shared__ unsigned short sx[2][NROWS * RP];   // 2 x 18,496 B
    __shared__ float sctx[CPG];

    const int bx = blockIdx.x;          // 1024 blocks = n(32) * g(4) * tileblock(8)
    const int tb = bx & 7;
    const int g  = (bx >> 3) & 3;
    const int n  = bx >> 5;
    const int tid  = threadIdx.x;
    const int lane = tid & 63;
    const int wv   = tid >> 6;

    if (tid < CPG) sctx[tid] = ctxb[n * COUT + g * CPG + tid];

    const float* xb = x + ((size_t)(n * CIN + g * CPG)) * LIN;

    // Staging geometry: rows 4..131 from 32 l-quads (q4=1..32), 64 ci.
    const int cqb = 4 * wv + (lane >> 4);   // ci-quad (4 rows) 0..15
    const int q4a = 1 + (lane & 15);        // base l-quad

    float4v mv[8];   // main-tile loads in flight
    float4v hv[2];   // halo loads (threads 0..63)

    auto issue_main = [&](int l0) {
        #pragma unroll
        for (int i = 0; i < 2; ++i) {
            int lg = l0 - 4 + 4 * (q4a + 16 * i);
            #pragma unroll
            for (int j = 0; j < 4; ++j)
                mv[4 * i + j] = *(const float4v*)(xb + (size_t)(4 * cqb + j) * LIN + lg);
        }
    };
    auto issue_halo = [&](int gt, int l0) {
        if (tid < 64) {
            int side = tid >> 5;                       // 0=head(rows0-3), 1=tail(rows132-135)
            bool ok  = side ? (gt < NTILES - 1) : (gt > 0);
            int lg   = side ? (l0 + LT) : (l0 - 4);
            int cr   = 4 * ((tid >> 1) & 15) + 2 * (tid & 1);
            #pragma unroll
            for (int j = 0; j < 2; ++j)
                hv[j] = ok ? *(const float4v*)(xb + (size_t)(cr + j) * LIN + lg)
                           : (float4v){0.f, 0.f, 0.f, 0.f};
        }
    };
    auto write_tile = [&](unsigned short* s) {
        #pragma unroll
        for (int i = 0; i < 2; ++i) {
            int row0 = 4 * (q4a + 16 * i);
            #pragma unroll
            for (int d = 0; d < 4; ++d) {
                ushort4v p;
                #pragma unroll
                for (int j = 0; j < 4; ++j)
                    p[j] = __builtin_bit_cast(unsigned short, __float2bfloat16(mv[4 * i + j][d]));
                *(ushort4v*)(&s[(row0 + d) * RP + 4 * cqb]) = p;
            }
        }
        if (tid < 64) {
            int side = tid >> 5;
            int row0 = side ? (NROWS - 4) : 0;
            int off  = 4 * ((tid >> 1) & 15) + 2 * (tid & 1);
            #pragma unroll
            for (int d = 0; d < 4; ++d) {
                unsigned int pp =
                    (unsigned int)__builtin_bit_cast(unsigned short, __float2bfloat16(hv[0][d]))
                  | ((unsigned int)__builtin_bit_cast(unsigned short, __float2bfloat16(hv[1][d])) << 16);
                *(unsigned int*)(&s[(row0 + d) * RP + off]) = pp;
            }
        }
    };

    const int r  = lane & 15;
    const int q  = lane >> 4;
    const int wl = (wv >> 1) * 64;          // wave l-offset within tile
    const int wc = (wv & 1) * 32;           // wave co-offset within group
    const int c0 = (wv & 1) * 2;            // co16 base index

    const short8* wFp = (const short8*)wF;
    const int gt0 = tb * TPB;

    issue_main(gt0 * LT);
    issue_halo(gt0, gt0 * LT);
    write_tile(sx[0]);
    __syncthreads();

    for (int it = 0; it < TPB; ++it) {
        const int gt = gt0 + it;
        const int l0 = gt * LT;

        if (it + 1 < TPB) {                  // prefetch next tile into registers
            issue_main(l0 + LT);
            issue_halo(gt + 1, l0 + LT);
        }

        const unsigned short* s = sx[it & 1];
        float4v acc[2][4];
        #pragma unroll
        for (int a = 0; a < 2; ++a)
            #pragma unroll
            for (int b = 0; b < 4; ++b)
                acc[a][b] = (float4v){0.f, 0.f, 0.f, 0.f};

        #pragma unroll
        for (int k = 0; k < KW; ++k) {
            #pragma unroll
            for (int chunk = 0; chunk < 2; ++chunk) {
                short8 bfrag[4];
                #pragma unroll
                for (int l16 = 0; l16 < 4; ++l16) {
                    int base = (wl + l16 * 16 + r + k) * RP + chunk * 32 + q * 8;
                    short4v lo = *(const short4v*)(&s[base]);
                    short4v hi = *(const short4v*)(&s[base + 4]);
                    bfrag[l16] = __builtin_shufflevector(lo, hi, 0, 1, 2, 3, 4, 5, 6, 7);
                }
                short8 afrag[2];
                #pragma unroll
                for (int c2 = 0; c2 < 2; ++c2)
                    afrag[c2] = wFp[(((g * 4 + c0 + c2) * 9 + k) * 2 + chunk) * 64 + lane];
                #pragma unroll
                for (int c2 = 0; c2 < 2; ++c2)
                    #pragma unroll
                    for (int l16 = 0; l16 < 4; ++l16)
                        acc[c2][l16] = __builtin_amdgcn_mfma_f32_16x16x32_bf16(
                            afrag[c2], bfrag[l16], acc[c2][l16], 0, 0, 0);
            }
        }

        if (it + 1 < TPB) write_tile(sx[(it + 1) & 1]);

        // Epilogue: D layout col = lane&15 (l), row = q*4+reg (co). Add ctx+bias, store.
        float* ob = out + ((size_t)(n * COUT + g * CPG)) * LIN + l0 + wl;
        #pragma unroll
        for (int c2 = 0; c2 < 2; ++c2) {
            #pragma unroll
            for (int reg = 0; reg < 4; ++reg) {
                int co_l = wc + c2 * 16 + q * 4 + reg;
                float add = sctx[co_l];
                #pragma unroll
                for (int l16 = 0; l16 < 4; ++l16)
                    ob[(size_t)co_l * LIN + l16 * 16 + r] = acc[c2][l16][reg] + add;
            }
        }

        if (it + 1 < TPB) __syncthreads();
    }
}

extern "C" void kernel_launch(void* const* d_in, const int* in_sizes, int n_in,
                              void* d_out, int out_size, void* d_ws, size_t ws_size,
                              hipStream_t stream) {
    const float* x    = (const float*)d_in[0];   // (32, 256, 4096)
    const float* c    = (const float*)d_in[1];   // (32, 128)
    const float* w    = (const float*)d_in[2];   // (256, 64, 9)
    const float* cw   = (const float*)d_in[3];   // (256, 128)
    const float* bias = (const float*)d_in[4];   // (256,)
    float* out = (float*)d_out;                  // (32, 256, 4096)

    __hip_bfloat16* wF = (__hip_bfloat16*)d_ws;                       // 589,824 B
    float* ctxb = (float*)((char*)d_ws + (size_t)WF_ELEMS * 2);       // 32,768 B

    pack_weights<<<(WF_ELEMS + 255) / 256, 256, 0, stream>>>(w, wF);
    ctx_kernel<<<(NB * COUT * 64) / 256, 256, 0, stream>>>(c, cw, bias, ctxb);
    conv_mfma<<<NB * NGRP * (NTILES / TPB), 256, 0, stream>>>(x, wF, ctxb, out);
}